// Round 20
// baseline (150.529 us; speedup 1.0000x reference)
//
#include <hip/hip_runtime.h>
#include <hip/hip_bf16.h>

#define BB 2048
#define NN 4096
#define MM 4096
#define HH 64
#define KSPLIT 8

using f32x4  = __attribute__((ext_vector_type(4))) float;
using bf16x8 = __attribute__((ext_vector_type(8))) short;

__device__ __forceinline__ unsigned int cvtpk(float lo, float hi) {
    unsigned int r;
    asm("v_cvt_pk_bf16_f32 %0, %1, %2" : "=v"(r) : "v"(lo), "v"(hi));
    return r;   // D.b16[0]=cvt(lo), D.b16[1]=cvt(hi)
}

__device__ __forceinline__ unsigned short f2bf(float f) {
    union { float f; unsigned int u; } v; v.f = f;
    unsigned int r = ((v.u >> 16) & 1u) + 0x7FFFu;   // round-to-nearest-even
    return (unsigned short)((v.u + r) >> 16);
}

__device__ __forceinline__ float bf2f(unsigned short s) {
    union { unsigned int u; float f; } v; v.u = ((unsigned int)s) << 16;
    return v.f;
}

#define CPLDS16(g, l) __builtin_amdgcn_global_load_lds( \
    (const __attribute__((address_space(1))) unsigned int*)(g), \
    (__attribute__((address_space(3))) unsigned int*)(l), 16, 0, 0)

// ============ K1: identical to passing R19 ============
__global__ __launch_bounds__(256, 3) void k_front(const float* __restrict__ x,
                                                  const float* __restrict__ w1,
                                                  const float* __restrict__ tab,
                                                  const float* __restrict__ hw,
                                                  const float* __restrict__ hb,
                                                  unsigned char* __restrict__ bits_b,
                                                  signed char* __restrict__ tq8,
                                                  float* __restrict__ tsc,
                                                  float* __restrict__ wdq,
                                                  unsigned short* __restrict__ hpart,
                                                  float* __restrict__ out) {
    __shared__ float lA[64 * 128];   // 32 KB (f32 x-tile, swizzled via source)
    __shared__ short lB[64 * 128];   // 16 KB (bf16 w1-tile, swizzled)
    __shared__ float red[4];
    int id = blockIdx.x;
    int t = threadIdx.x;
    int lane = t & 63, wid = t >> 6;

    if (id < 256) {
        // XCD-chunked bijection (256 = 8 XCDs x 32): same-ks blocks share one XCD's L2
        int swz = (id & 7) * 32 + (id >> 3);
        int bx = swz & 31, ks = swz >> 5;       // 32 b-tiles x 8 k-splits
        int b0 = bx * 64;
        int row = lane & 15, grp = lane >> 4;
        int R = wid * 16 + row;
        int swA = (R & 7) << 4;
        f32x4 acc[4] = {};

        #pragma unroll
        for (int kc = 0; kc < 4; ++kc) {
            int k0 = ks * 512 + kc * 128;
            if (kc) __syncthreads();            // all waves done reading LDS prev chunk

            // ---- stage A via global_load_lds: LDS linear, source col pre-swizzled (^ row&7)
            #pragma unroll
            for (int i = 0; i < 8; ++i) {
                int cbase = i * 256 + wid * 64;
                int c = cbase + lane;
                int r2 = c >> 5;
                int sem = (c & 31) ^ (r2 & 7);
                CPLDS16(x + (size_t)(b0 + r2) * NN + k0 + sem * 4, (char*)lA + cbase * 16);
            }
            // ---- stage B: w1 f32 -> bf16 in-kernel
            #pragma unroll
            for (int i = 0; i < 4; ++i) {
                int c = t + i * 256;
                int r2 = c >> 4, col8 = c & 15;
                const float* p = w1 + (size_t)r2 * NN + k0 + col8 * 8;
                f32x4 q0 = *(const f32x4*)p;
                f32x4 q1 = *(const f32x4*)(p + 4);
                union { unsigned int u[4]; bf16x8 v; } Bv;
                Bv.u[0] = cvtpk(q0[0], q0[1]);
                Bv.u[1] = cvtpk(q0[2], q0[3]);
                Bv.u[2] = cvtpk(q1[0], q1[1]);
                Bv.u[3] = cvtpk(q1[2], q1[3]);
                *(bf16x8*)((char*)lB + ((r2 * 256 + col8 * 16) ^ ((r2 & 7) << 4))) = Bv.v;
            }
            __syncthreads();

            #pragma unroll
            for (int kk = 0; kk < 4; ++kk) {
                int rawA = R * 512 + kk * 128 + grp * 32;
                f32x4 a0 = *(const f32x4*)((const char*)lA + ((rawA) ^ swA));
                f32x4 a1 = *(const f32x4*)((const char*)lA + ((rawA + 16) ^ swA));
                unsigned int sb = 0;
                #pragma unroll
                for (int e = 0; e < 4; ++e) {
                    sb |= (a0[e] > 0.0f ? 1u : 0u) << e;
                    sb |= (a1[e] > 0.0f ? 1u : 0u) << (e + 4);
                }
                bits_b[(size_t)((k0 >> 3) + kk * 4 + grp) * BB + b0 + R] = (unsigned char)sb;

                union { unsigned int u[4]; bf16x8 v; } A;
                A.u[0] = cvtpk(a0[0], a0[1]);
                A.u[1] = cvtpk(a0[2], a0[3]);
                A.u[2] = cvtpk(a1[0], a1[1]);
                A.u[3] = cvtpk(a1[2], a1[3]);
                #pragma unroll
                for (int h = 0; h < 4; ++h) {
                    int hr = h * 16 + row;
                    int rawB = hr * 256 + kk * 64 + grp * 16;
                    bf16x8 bf = *(const bf16x8*)((const char*)lB + (rawB ^ ((hr & 7) << 4)));
                    acc[h] = __builtin_amdgcn_mfma_f32_16x16x32_bf16(A.v, bf, acc[h], 0, 0, 0);
                }
            }
        }
        #pragma unroll
        for (int h = 0; h < 4; ++h) {
            #pragma unroll
            for (int r = 0; r < 4; ++r) {
                int bb = b0 + wid * 16 + grp * 4 + r;   // C/D: row=(lane>>4)*4+reg
                int hh = h * 16 + row;                   // C/D: col=lane&15
                hpart[((size_t)ks * BB + bb) * HH + hh] = f2bf(acc[h][r]);
            }
        }
    } else if (id < 1280) {
        // ---- quantize ram_tables -> i8 + scale; one row per wave
        int rowm = (id - 256) * 4 + wid;
        f32x4 v = *(const f32x4*)(tab + (size_t)rowm * 256 + lane * 4);
        float a = fmaxf(fmaxf(fabsf(v[0]), fabsf(v[1])), fmaxf(fabsf(v[2]), fabsf(v[3])));
        #pragma unroll
        for (int off = 32; off; off >>= 1) a = fmaxf(a, __shfl_xor(a, off));
        float scale = fmaxf(a, 1e-6f) / 127.0f;
        char4 o;
        #pragma unroll
        for (int e = 0; e < 4; ++e) {
            float q = rintf(v[e] / scale);
            q = fminf(fmaxf(q, -127.0f), 127.0f);
            ((signed char*)&o)[e] = (signed char)(int)q;
        }
        *(char4*)(tq8 + (size_t)rowm * 256 + lane * 4) = o;
        if (lane == 0) tsc[rowm] = scale;
    } else if (id == 1280) {
        // ---- quantize halt_w
        float vals[16];
        float a = 0.f;
        #pragma unroll
        for (int i = 0; i < 16; ++i) { vals[i] = hw[t * 16 + i]; a = fmaxf(a, fabsf(vals[i])); }
        #pragma unroll
        for (int off = 32; off; off >>= 1) a = fmaxf(a, __shfl_xor(a, off));
        if (lane == 0) red[wid] = a;
        __syncthreads();
        float m = fmaxf(fmaxf(red[0], red[1]), fmaxf(red[2], red[3]));
        float scale = fmaxf(m, 1e-6f) / 127.0f;
        #pragma unroll
        for (int i = 0; i < 16; ++i) {
            float q = rintf(vals[i] / scale);
            q = fminf(fmaxf(q, -127.0f), 127.0f);
            wdq[t * 16 + i] = q * scale;
        }
    } else {
        // ---- init out[2b+1] = halt bias
        int b = (id - 1281) * 256 + t;
        out[b * 2 + 1] = hb[0];
    }
}

// ============ K2: DIAGNOSTIC — gather phase repeated x12 (stage once; identical arithmetic
// each rep; asm-sink keeps reps live; atomics/engage fire once after last rep).
__global__ __launch_bounds__(256) void k_back(const unsigned char* __restrict__ bits_b,
                                              const int* __restrict__ conn,
                                              const signed char* __restrict__ tq8,
                                              const float* __restrict__ tsc,
                                              const float* __restrict__ wdq,
                                              const unsigned short* __restrict__ hpart,
                                              const float* __restrict__ b1,
                                              const float* __restrict__ w2,
                                              const float* __restrict__ b2,
                                              float* __restrict__ out) {
    extern __shared__ char sm[];
    unsigned char* lbits = (unsigned char*)sm;         // [512 g][64 b]  32 KB
    signed char*   ltab  = (signed char*)(sm + 32768); // [128 m][256]   32 KB
    float*         red2  = (float*)(sm + 65536);       // [4][64]         1 KB

    int id = blockIdx.x;
    int t = threadIdx.x;
    int lane = t & 63, wid = t >> 6;

    // XCD-chunked bijection (1024 = 8 x 128): ltab/bits reuse becomes XCD-local.
    int swz = (id & 7) * 128 + (id >> 3);
    int bx = swz & 31, my = swz >> 5;
    int b0 = bx * 64, m0 = my * 128;

    for (int i = t; i < 2048; i += 256) {
        int g = i >> 2, q = i & 3;
        ((uint4*)lbits)[i] = *(const uint4*)(bits_b + (size_t)g * BB + b0 + q * 16);
    }
    for (int i = t; i < 2048; i += 256) {
        ((uint4*)ltab)[i] = *(const uint4*)(tq8 + (size_t)m0 * 256 + i * 16);
    }
    __syncthreads();

    int grp = lane >> 4;
    int bq  = lane & 15;
    float acc0 = 0.f, acc1 = 0.f, acc2 = 0.f, acc3 = 0.f;

    for (int rep = 0; rep < 12; ++rep) {       // DIAGNOSTIC reps; identical result each time
        acc0 = 0.f; acc1 = 0.f; acc2 = 0.f; acc3 = 0.f;
        #pragma unroll 2
        for (int qi = 0; qi < 8; ++qi) {
            int mb = m0 + wid * 32 + qi * 4;
            int mloc = wid * 32 + qi * 4 + grp;
            float vw0 = tsc[mb + 0] * wdq[mb + 0];
            float vw1 = tsc[mb + 1] * wdq[mb + 1];
            float vw2 = tsc[mb + 2] * wdq[mb + 2];
            float vw3 = tsc[mb + 3] * wdq[mb + 3];
            float vw = grp == 0 ? vw0 : grp == 1 ? vw1 : grp == 2 ? vw2 : vw3;

            unsigned int aq = 0;
            #pragma unroll
            for (int k = 0; k < 8; ++k) {
                int c0 = conn[(mb + 0) * 8 + k];
                int c1 = conn[(mb + 1) * 8 + k];
                int c2 = conn[(mb + 2) * 8 + k];
                int c3 = conn[(mb + 3) * 8 + k];
                int g  = grp == 0 ? (c0 >> 3) : grp == 1 ? (c1 >> 3) : grp == 2 ? (c2 >> 3) : (c3 >> 3);
                int sh = grp == 0 ? (c0 & 7)  : grp == 1 ? (c1 & 7)  : grp == 2 ? (c2 & 7)  : (c3 & 7);
                unsigned int w32 = *(const unsigned int*)(lbits + g * 64 + bq * 4);
                aq |= ((w32 >> sh) & 0x01010101u) << k;
            }
            const signed char* rowp = ltab + mloc * 256;
            float q0 = (float)rowp[aq & 255];
            float q1 = (float)rowp[(aq >> 8) & 255];
            float q2 = (float)rowp[(aq >> 16) & 255];
            float q3 = (float)rowp[aq >> 24];
            acc0 = fmaf(q0, vw, acc0); acc1 = fmaf(q1, vw, acc1);
            acc2 = fmaf(q2, vw, acc2); acc3 = fmaf(q3, vw, acc3);
        }
        // keep this rep's results live without storing (rule #17: anti-DCE sink)
        asm volatile("" :: "v"(acc0), "v"(acc1), "v"(acc2), "v"(acc3));
    }

    acc0 += __shfl_xor(acc0, 16); acc1 += __shfl_xor(acc1, 16);
    acc2 += __shfl_xor(acc2, 16); acc3 += __shfl_xor(acc3, 16);
    acc0 += __shfl_xor(acc0, 32); acc1 += __shfl_xor(acc1, 32);
    acc2 += __shfl_xor(acc2, 32); acc3 += __shfl_xor(acc3, 32);
    if (lane < 16) {
        float4 o = make_float4(acc0, acc1, acc2, acc3);
        *(float4*)(red2 + wid * 64 + bq * 4) = o;
    }
    __syncthreads();
    if (t < 64) {
        float s = red2[t] + red2[64 + t] + red2[128 + t] + red2[192 + t];
        atomicAdd(&out[(size_t)(b0 + t) * 2 + 1], s);
    }

    // ---- engage fold: waves 0,1 handle b = 2*id + wid (raw id; independent of halt LDS)
    if (wid < 2) {
        int b = id * 2 + wid;
        float s = 0.f;
        #pragma unroll
        for (int ks = 0; ks < KSPLIT; ++ks) s += bf2f(hpart[((size_t)ks * BB + b) * HH + lane]);
        s += b1[lane];
        s = fmaxf(s, 0.f);
        s *= w2[lane];
        #pragma unroll
        for (int off = 32; off; off >>= 1) s += __shfl_xor(s, off);
        if (lane == 0) out[b * 2] = s + b2[0];
    }
}

extern "C" void kernel_launch(void* const* d_in, const int* in_sizes, int n_in,
                              void* d_out, int out_size, void* d_ws, size_t ws_size,
                              hipStream_t stream) {
    const float* x    = (const float*)d_in[0];
    const float* tab  = (const float*)d_in[1];
    const float* w1   = (const float*)d_in[2];
    const float* b1   = (const float*)d_in[3];
    const float* w2   = (const float*)d_in[4];
    const float* b2   = (const float*)d_in[5];
    const float* hw   = (const float*)d_in[6];
    const float* hb   = (const float*)d_in[7];
    const int*   conn = (const int*)d_in[8];
    float* out = (float*)d_out;

    char* ws = (char*)d_ws;
    signed char*    tq8    = (signed char*)(ws);               //  1,048,576 B
    float*          tsc    = (float*)(ws + 1048576);           //     16,384 B
    float*          wdq    = (float*)(ws + 1064960);           //     16,384 B
    unsigned char*  bits_b = (unsigned char*)(ws + 1081344);   //  1,048,576 B
    unsigned short* hpart  = (unsigned short*)(ws + 2129920);  //  2,097,152 B (bf16, 8 splits)

    k_front<<<1289, 256, 0, stream>>>(x, w1, tab, hw, hb, bits_b, tq8, tsc, wdq, hpart, out);
    k_back<<<1024, 256, 66560, stream>>>(bits_b, conn, tq8, tsc, wdq, hpart, b1, w2, b2, out);
}

// Round 21
// 29.281 us; speedup vs baseline: 5.1409x; 5.1409x over previous
//
#include <hip/hip_runtime.h>
#include <hip/hip_bf16.h>

#define BB 2048
#define NN 4096
#define MM 4096
#define HH 64
#define KSPLIT 8

using f32x4  = __attribute__((ext_vector_type(4))) float;
using bf16x8 = __attribute__((ext_vector_type(8))) short;

__device__ __forceinline__ unsigned int cvtpk(float lo, float hi) {
    unsigned int r;
    asm("v_cvt_pk_bf16_f32 %0, %1, %2" : "=v"(r) : "v"(lo), "v"(hi));
    return r;   // D.b16[0]=cvt(lo), D.b16[1]=cvt(hi)
}

__device__ __forceinline__ unsigned short f2bf(float f) {
    union { float f; unsigned int u; } v; v.f = f;
    unsigned int r = ((v.u >> 16) & 1u) + 0x7FFFu;   // round-to-nearest-even
    return (unsigned short)((v.u + r) >> 16);
}

__device__ __forceinline__ float bf2f(unsigned short s) {
    union { unsigned int u; float f; } v; v.u = ((unsigned int)s) << 16;
    return v.f;
}

#define CPLDS16(g, l) __builtin_amdgcn_global_load_lds( \
    (const __attribute__((address_space(1))) unsigned int*)(g), \
    (__attribute__((address_space(3))) unsigned int*)(l), 16, 0, 0)

// ============ K1: identical to passing R19 ============
__global__ __launch_bounds__(256, 3) void k_front(const float* __restrict__ x,
                                                  const float* __restrict__ w1,
                                                  const float* __restrict__ tab,
                                                  const float* __restrict__ hw,
                                                  const float* __restrict__ hb,
                                                  unsigned char* __restrict__ bits_b,
                                                  signed char* __restrict__ tq8,
                                                  float* __restrict__ tsc,
                                                  float* __restrict__ wdq,
                                                  unsigned short* __restrict__ hpart,
                                                  float* __restrict__ out) {
    __shared__ float lA[64 * 128];   // 32 KB (f32 x-tile, swizzled via source)
    __shared__ short lB[64 * 128];   // 16 KB (bf16 w1-tile, swizzled)
    __shared__ float red[4];
    int id = blockIdx.x;
    int t = threadIdx.x;
    int lane = t & 63, wid = t >> 6;

    if (id < 256) {
        // XCD-chunked bijection (256 = 8 XCDs x 32): same-ks blocks share one XCD's L2
        int swz = (id & 7) * 32 + (id >> 3);
        int bx = swz & 31, ks = swz >> 5;       // 32 b-tiles x 8 k-splits
        int b0 = bx * 64;
        int row = lane & 15, grp = lane >> 4;
        int R = wid * 16 + row;
        int swA = (R & 7) << 4;
        f32x4 acc[4] = {};

        #pragma unroll
        for (int kc = 0; kc < 4; ++kc) {
            int k0 = ks * 512 + kc * 128;
            if (kc) __syncthreads();            // all waves done reading LDS prev chunk

            // ---- stage A via global_load_lds: LDS linear, source col pre-swizzled (^ row&7)
            #pragma unroll
            for (int i = 0; i < 8; ++i) {
                int cbase = i * 256 + wid * 64;
                int c = cbase + lane;
                int r2 = c >> 5;
                int sem = (c & 31) ^ (r2 & 7);
                CPLDS16(x + (size_t)(b0 + r2) * NN + k0 + sem * 4, (char*)lA + cbase * 16);
            }
            // ---- stage B: w1 f32 -> bf16 in-kernel
            #pragma unroll
            for (int i = 0; i < 4; ++i) {
                int c = t + i * 256;
                int r2 = c >> 4, col8 = c & 15;
                const float* p = w1 + (size_t)r2 * NN + k0 + col8 * 8;
                f32x4 q0 = *(const f32x4*)p;
                f32x4 q1 = *(const f32x4*)(p + 4);
                union { unsigned int u[4]; bf16x8 v; } Bv;
                Bv.u[0] = cvtpk(q0[0], q0[1]);
                Bv.u[1] = cvtpk(q0[2], q0[3]);
                Bv.u[2] = cvtpk(q1[0], q1[1]);
                Bv.u[3] = cvtpk(q1[2], q1[3]);
                *(bf16x8*)((char*)lB + ((r2 * 256 + col8 * 16) ^ ((r2 & 7) << 4))) = Bv.v;
            }
            __syncthreads();

            #pragma unroll
            for (int kk = 0; kk < 4; ++kk) {
                int rawA = R * 512 + kk * 128 + grp * 32;
                f32x4 a0 = *(const f32x4*)((const char*)lA + ((rawA) ^ swA));
                f32x4 a1 = *(const f32x4*)((const char*)lA + ((rawA + 16) ^ swA));
                unsigned int sb = 0;
                #pragma unroll
                for (int e = 0; e < 4; ++e) {
                    sb |= (a0[e] > 0.0f ? 1u : 0u) << e;
                    sb |= (a1[e] > 0.0f ? 1u : 0u) << (e + 4);
                }
                bits_b[(size_t)((k0 >> 3) + kk * 4 + grp) * BB + b0 + R] = (unsigned char)sb;

                union { unsigned int u[4]; bf16x8 v; } A;
                A.u[0] = cvtpk(a0[0], a0[1]);
                A.u[1] = cvtpk(a0[2], a0[3]);
                A.u[2] = cvtpk(a1[0], a1[1]);
                A.u[3] = cvtpk(a1[2], a1[3]);
                #pragma unroll
                for (int h = 0; h < 4; ++h) {
                    int hr = h * 16 + row;
                    int rawB = hr * 256 + kk * 64 + grp * 16;
                    bf16x8 bf = *(const bf16x8*)((const char*)lB + (rawB ^ ((hr & 7) << 4)));
                    acc[h] = __builtin_amdgcn_mfma_f32_16x16x32_bf16(A.v, bf, acc[h], 0, 0, 0);
                }
            }
        }
        #pragma unroll
        for (int h = 0; h < 4; ++h) {
            #pragma unroll
            for (int r = 0; r < 4; ++r) {
                int bb = b0 + wid * 16 + grp * 4 + r;   // C/D: row=(lane>>4)*4+reg
                int hh = h * 16 + row;                   // C/D: col=lane&15
                hpart[((size_t)ks * BB + bb) * HH + hh] = f2bf(acc[h][r]);
            }
        }
    } else if (id < 1280) {
        // ---- quantize ram_tables -> i8 + scale; one row per wave
        int rowm = (id - 256) * 4 + wid;
        f32x4 v = *(const f32x4*)(tab + (size_t)rowm * 256 + lane * 4);
        float a = fmaxf(fmaxf(fabsf(v[0]), fabsf(v[1])), fmaxf(fabsf(v[2]), fabsf(v[3])));
        #pragma unroll
        for (int off = 32; off; off >>= 1) a = fmaxf(a, __shfl_xor(a, off));
        float scale = fmaxf(a, 1e-6f) / 127.0f;
        char4 o;
        #pragma unroll
        for (int e = 0; e < 4; ++e) {
            float q = rintf(v[e] / scale);
            q = fminf(fmaxf(q, -127.0f), 127.0f);
            ((signed char*)&o)[e] = (signed char)(int)q;
        }
        *(char4*)(tq8 + (size_t)rowm * 256 + lane * 4) = o;
        if (lane == 0) tsc[rowm] = scale;
    } else if (id == 1280) {
        // ---- quantize halt_w
        float vals[16];
        float a = 0.f;
        #pragma unroll
        for (int i = 0; i < 16; ++i) { vals[i] = hw[t * 16 + i]; a = fmaxf(a, fabsf(vals[i])); }
        #pragma unroll
        for (int off = 32; off; off >>= 1) a = fmaxf(a, __shfl_xor(a, off));
        if (lane == 0) red[wid] = a;
        __syncthreads();
        float m = fmaxf(fmaxf(red[0], red[1]), fmaxf(red[2], red[3]));
        float scale = fmaxf(m, 1e-6f) / 127.0f;
        #pragma unroll
        for (int i = 0; i < 16; ++i) {
            float q = rintf(vals[i] / scale);
            q = fminf(fmaxf(q, -127.0f), 127.0f);
            wdq[t * 16 + i] = q * scale;
        }
    } else {
        // ---- init out[2b+1] = halt bias
        int b = (id - 1281) * 256 + t;
        out[b * 2 + 1] = hb[0];
    }
}

// ============ K2: 1024 blocks x 512 threads (8 waves, 16 m/wave) — select-free gather,
//               16 waves/CU (66 KB LDS, 2 blocks/CU) + engage fold (waves 0-1)
__global__ __launch_bounds__(512) void k_back(const unsigned char* __restrict__ bits_b,
                                              const int* __restrict__ conn,
                                              const signed char* __restrict__ tq8,
                                              const float* __restrict__ tsc,
                                              const float* __restrict__ wdq,
                                              const unsigned short* __restrict__ hpart,
                                              const float* __restrict__ b1,
                                              const float* __restrict__ w2,
                                              const float* __restrict__ b2,
                                              float* __restrict__ out) {
    extern __shared__ char sm[];
    unsigned char* lbits = (unsigned char*)sm;         // [512 g][64 b]  32 KB
    signed char*   ltab  = (signed char*)(sm + 32768); // [128 m][256]   32 KB
    float*         red2  = (float*)(sm + 65536);       // [8][64]         2 KB

    int id = blockIdx.x;
    int t = threadIdx.x;                 // 0..511
    int lane = t & 63, wid = t >> 6;     // wid 0..7

    // XCD-chunked bijection (1024 = 8 x 128): ltab/bits reuse becomes XCD-local.
    int swz = (id & 7) * 128 + (id >> 3);
    int bx = swz & 31, my = swz >> 5;
    int b0 = bx * 64, m0 = my * 128;

    for (int i = t; i < 2048; i += 512) {
        int g = i >> 2, q = i & 3;
        ((uint4*)lbits)[i] = *(const uint4*)(bits_b + (size_t)g * BB + b0 + q * 16);
    }
    for (int i = t; i < 2048; i += 512) {
        ((uint4*)ltab)[i] = *(const uint4*)(tq8 + (size_t)m0 * 256 + i * 16);
    }
    __syncthreads();

    int grp = lane >> 4;
    int bq  = lane & 15;
    float acc0 = 0.f, acc1 = 0.f, acc2 = 0.f, acc3 = 0.f;

    #pragma unroll
    for (int qi = 0; qi < 4; ++qi) {
        int mloc = wid * 16 + qi * 4 + grp;     // this lane's local m
        int mg   = m0 + mloc;                    // global m
        float vw = tsc[mg] * wdq[mg];            // per-lane, 4 distinct/wave, L2
        int4 ca = *(const int4*)(conn + (size_t)mg * 8);      // k 0..3
        int4 cb = *(const int4*)(conn + (size_t)mg * 8 + 4);  // k 4..7

        unsigned int aq = 0;
        #define GB(cv, kk) { \
            unsigned int w32 = *(const unsigned int*)(lbits + ((cv) >> 3) * 64 + bq * 4); \
            aq |= (((w32) >> ((cv) & 7)) & 0x01010101u) << (kk); }
        GB(ca.x, 0) GB(ca.y, 1) GB(ca.z, 2) GB(ca.w, 3)
        GB(cb.x, 4) GB(cb.y, 5) GB(cb.z, 6) GB(cb.w, 7)
        #undef GB

        const signed char* rowp = ltab + mloc * 256;
        float q0 = (float)rowp[aq & 255];
        float q1 = (float)rowp[(aq >> 8) & 255];
        float q2 = (float)rowp[(aq >> 16) & 255];
        float q3 = (float)rowp[aq >> 24];
        acc0 = fmaf(q0, vw, acc0); acc1 = fmaf(q1, vw, acc1);
        acc2 = fmaf(q2, vw, acc2); acc3 = fmaf(q3, vw, acc3);
    }

    // combine the 4 m-groups (lanes xor 16, xor 32) -> per-wave partial for 64 b's
    acc0 += __shfl_xor(acc0, 16); acc1 += __shfl_xor(acc1, 16);
    acc2 += __shfl_xor(acc2, 16); acc3 += __shfl_xor(acc3, 16);
    acc0 += __shfl_xor(acc0, 32); acc1 += __shfl_xor(acc1, 32);
    acc2 += __shfl_xor(acc2, 32); acc3 += __shfl_xor(acc3, 32);
    if (lane < 16) {
        float4 o = make_float4(acc0, acc1, acc2, acc3);
        *(float4*)(red2 + wid * 64 + bq * 4) = o;
    }
    __syncthreads();
    if (t < 64) {
        float s = 0.f;
        #pragma unroll
        for (int w = 0; w < 8; ++w) s += red2[w * 64 + t];
        atomicAdd(&out[(size_t)(b0 + t) * 2 + 1], s);
    }

    // ---- engage fold: waves 0,1 handle b = 2*id + wid (raw id; independent of halt LDS)
    if (wid < 2) {
        int b = id * 2 + wid;
        float s = 0.f;
        #pragma unroll
        for (int ks = 0; ks < KSPLIT; ++ks) s += bf2f(hpart[((size_t)ks * BB + b) * HH + lane]);
        s += b1[lane];
        s = fmaxf(s, 0.f);
        s *= w2[lane];
        #pragma unroll
        for (int off = 32; off; off >>= 1) s += __shfl_xor(s, off);
        if (lane == 0) out[b * 2] = s + b2[0];
    }
}

extern "C" void kernel_launch(void* const* d_in, const int* in_sizes, int n_in,
                              void* d_out, int out_size, void* d_ws, size_t ws_size,
                              hipStream_t stream) {
    const float* x    = (const float*)d_in[0];
    const float* tab  = (const float*)d_in[1];
    const float* w1   = (const float*)d_in[2];
    const float* b1   = (const float*)d_in[3];
    const float* w2   = (const float*)d_in[4];
    const float* b2   = (const float*)d_in[5];
    const float* hw   = (const float*)d_in[6];
    const float* hb   = (const float*)d_in[7];
    const int*   conn = (const int*)d_in[8];
    float* out = (float*)d_out;

    char* ws = (char*)d_ws;
    signed char*    tq8    = (signed char*)(ws);               //  1,048,576 B
    float*          tsc    = (float*)(ws + 1048576);           //     16,384 B
    float*          wdq    = (float*)(ws + 1064960);           //     16,384 B
    unsigned char*  bits_b = (unsigned char*)(ws + 1081344);   //  1,048,576 B
    unsigned short* hpart  = (unsigned short*)(ws + 2129920);  //  2,097,152 B (bf16, 8 splits)

    k_front<<<1289, 256, 0, stream>>>(x, w1, tab, hw, hb, bits_b, tq8, tsc, wdq, hpart, out);
    k_back<<<1024, 512, 67584, stream>>>(bits_b, conn, tq8, tsc, wdq, hpart, b1, w2, b2, out);
}

// Round 22
// 28.821 us; speedup vs baseline: 5.2228x; 1.0159x over previous
//
#include <hip/hip_runtime.h>
#include <hip/hip_bf16.h>

#define BB 2048
#define NN 4096
#define MM 4096
#define HH 64
#define KSPLIT 8

using f32x4  = __attribute__((ext_vector_type(4))) float;
using bf16x8 = __attribute__((ext_vector_type(8))) short;

__device__ __forceinline__ unsigned int cvtpk(float lo, float hi) {
    unsigned int r;
    asm("v_cvt_pk_bf16_f32 %0, %1, %2" : "=v"(r) : "v"(lo), "v"(hi));
    return r;   // D.b16[0]=cvt(lo), D.b16[1]=cvt(hi)
}

__device__ __forceinline__ unsigned short f2bf(float f) {
    union { float f; unsigned int u; } v; v.f = f;
    unsigned int r = ((v.u >> 16) & 1u) + 0x7FFFu;   // round-to-nearest-even
    return (unsigned short)((v.u + r) >> 16);
}

__device__ __forceinline__ float bf2f(unsigned short s) {
    union { unsigned int u; float f; } v; v.u = ((unsigned int)s) << 16;
    return v.f;
}

// ============ K1: [0,256) gemm BM64/BK256x2, 512 thr, 8 waves (2 teams x 4) ============
//               | [256,768) table quant -> i8 | 768 halt_w quant | [769,773) out-halt init
__global__ __launch_bounds__(512, 4) void k_front(const float* __restrict__ x,
                                                  const float* __restrict__ w1,
                                                  const float* __restrict__ tab,
                                                  const float* __restrict__ hw,
                                                  const float* __restrict__ hb,
                                                  unsigned char* __restrict__ bits_b,
                                                  signed char* __restrict__ tq8,
                                                  float* __restrict__ tsc,
                                                  float* __restrict__ wdq,
                                                  unsigned short* __restrict__ hpart,
                                                  float* __restrict__ out) {
    __shared__ short lA[64 * 256];      // 32 KB bf16 x-tile (swizzled)
    __shared__ short lB[64 * 256];      // 32 KB bf16 w1-tile (swizzled)
    __shared__ char  scratch[16384];    // sby (2KB) during stage; team-merge (16KB) in epilogue
    int id = blockIdx.x;
    int t = threadIdx.x;                // 0..511
    int lane = t & 63, wid = t >> 6;    // wid 0..7

    if (id < 256) {
        // XCD-chunked bijection (256 = 8 XCDs x 32): same-ks blocks share one XCD's L2
        int swz = (id & 7) * 32 + (id >> 3);
        int bx = swz & 31, ks = swz >> 5;       // 32 b-tiles x 8 k-splits
        int b0 = bx * 64;
        int team = wid >> 2, w4 = wid & 3;
        int row = lane & 15, grp = lane >> 4;
        int R = w4 * 16 + row;
        int swA = (R & 7) << 4;
        unsigned char* sby = (unsigned char*)scratch;
        f32x4 acc[4] = {};

        #pragma unroll
        for (int kc = 0; kc < 2; ++kc) {
            int k0 = ks * 512 + kc * 256;
            if (kc) __syncthreads();            // protect lA/lB/sby being read

            // ---- stage A: x f32 -> bf16 LDS (swizzled) + sign bytes; coalesced 1KB/row-group
            #pragma unroll
            for (int i = 0; i < 4; ++i) {
                int c = t + i * 512;            // [0,2048): 64 rows x 32 col8
                int r2 = c >> 5, col8 = c & 31;
                const float* p = x + (size_t)(b0 + r2) * NN + k0 + col8 * 8;
                f32x4 a0 = *(const f32x4*)p;
                f32x4 a1 = *(const f32x4*)(p + 4);
                unsigned int sb = 0;
                #pragma unroll
                for (int e = 0; e < 4; ++e) {
                    sb |= (a0[e] > 0.0f ? 1u : 0u) << e;
                    sb |= (a1[e] > 0.0f ? 1u : 0u) << (e + 4);
                }
                sby[c] = (unsigned char)sb;
                union { unsigned int u[4]; bf16x8 v; } Av;
                Av.u[0] = cvtpk(a0[0], a0[1]);
                Av.u[1] = cvtpk(a0[2], a0[3]);
                Av.u[2] = cvtpk(a1[0], a1[1]);
                Av.u[3] = cvtpk(a1[2], a1[3]);
                *(bf16x8*)((char*)lA + ((r2 * 512 + col8 * 16) ^ ((r2 & 7) << 4))) = Av.v;
            }
            // ---- stage B: w1 f32 -> bf16 LDS (swizzled)
            #pragma unroll
            for (int i = 0; i < 4; ++i) {
                int c = t + i * 512;
                int r2 = c >> 5, col8 = c & 31;
                const float* p = w1 + (size_t)r2 * NN + k0 + col8 * 8;
                f32x4 q0 = *(const f32x4*)p;
                f32x4 q1 = *(const f32x4*)(p + 4);
                union { unsigned int u[4]; bf16x8 v; } Bv;
                Bv.u[0] = cvtpk(q0[0], q0[1]);
                Bv.u[1] = cvtpk(q0[2], q0[3]);
                Bv.u[2] = cvtpk(q1[0], q1[1]);
                Bv.u[3] = cvtpk(q1[2], q1[3]);
                *(bf16x8*)((char*)lB + ((r2 * 512 + col8 * 16) ^ ((r2 & 7) << 4))) = Bv.v;
            }
            __syncthreads();

            // ---- bits: dword-coalesced write from sby transpose (4 b-rows per dword)
            {
                int g = t >> 4, r4 = t & 15;    // g in [0,32), r4 in [0,16)
                unsigned int d = 0;
                #pragma unroll
                for (int e = 0; e < 4; ++e)
                    d |= (unsigned int)sby[(r4 * 4 + e) * 32 + g] << (e * 8);
                *(unsigned int*)(bits_b + (size_t)(ks * 64 + kc * 32 + g) * BB + b0 + r4 * 4) = d;
            }

            // ---- MFMA: team covers kk = team*4 .. team*4+3 (k-cols team*128..+128)
            #pragma unroll
            for (int kk4 = 0; kk4 < 4; ++kk4) {
                int kk = team * 4 + kk4;
                bf16x8 af = *(const bf16x8*)((const char*)lA +
                              ((R * 512 + kk * 64 + grp * 16) ^ swA));
                #pragma unroll
                for (int h = 0; h < 4; ++h) {
                    int hr = h * 16 + row;
                    bf16x8 bf = *(const bf16x8*)((const char*)lB +
                                  ((hr * 512 + kk * 64 + grp * 16) ^ ((hr & 7) << 4)));
                    acc[h] = __builtin_amdgcn_mfma_f32_16x16x32_bf16(af, bf, acc[h], 0, 0, 0);
                }
            }
        }

        // ---- merge team1 partials into team0, write hpart (bf16)
        __syncthreads();
        float* red = (float*)scratch;           // [16 planes][256]: conflict-free
        if (team == 1) {
            #pragma unroll
            for (int h = 0; h < 4; ++h)
                #pragma unroll
                for (int r = 0; r < 4; ++r)
                    red[(h * 4 + r) * 256 + w4 * 64 + lane] = acc[h][r];
        }
        __syncthreads();
        if (team == 0) {
            #pragma unroll
            for (int h = 0; h < 4; ++h) {
                #pragma unroll
                for (int r = 0; r < 4; ++r) {
                    float v = acc[h][r] + red[(h * 4 + r) * 256 + w4 * 64 + lane];
                    int bb = b0 + w4 * 16 + grp * 4 + r;   // C/D: row=(lane>>4)*4+reg
                    int hh = h * 16 + row;                  // C/D: col=lane&15
                    hpart[((size_t)ks * BB + bb) * HH + hh] = f2bf(v);
                }
            }
        }
    } else if (id < 768) {
        // ---- quantize ram_tables -> i8 + scale; one row per wave (8 rows/block)
        int rowm = (id - 256) * 8 + wid;
        f32x4 v = *(const f32x4*)(tab + (size_t)rowm * 256 + lane * 4);
        float a = fmaxf(fmaxf(fabsf(v[0]), fabsf(v[1])), fmaxf(fabsf(v[2]), fabsf(v[3])));
        #pragma unroll
        for (int off = 32; off; off >>= 1) a = fmaxf(a, __shfl_xor(a, off));
        float scale = fmaxf(a, 1e-6f) / 127.0f;
        char4 o;
        #pragma unroll
        for (int e = 0; e < 4; ++e) {
            float q = rintf(v[e] / scale);
            q = fminf(fmaxf(q, -127.0f), 127.0f);
            ((signed char*)&o)[e] = (signed char)(int)q;
        }
        *(char4*)(tq8 + (size_t)rowm * 256 + lane * 4) = o;
        if (lane == 0) tsc[rowm] = scale;
    } else if (id == 768) {
        // ---- quantize halt_w: 4096 elems, 8/thread
        float* r1 = (float*)scratch;
        float vals[8];
        float a = 0.f;
        #pragma unroll
        for (int i = 0; i < 8; ++i) { vals[i] = hw[t * 8 + i]; a = fmaxf(a, fabsf(vals[i])); }
        #pragma unroll
        for (int off = 32; off; off >>= 1) a = fmaxf(a, __shfl_xor(a, off));
        if (lane == 0) r1[wid] = a;
        __syncthreads();
        float m = r1[0];
        #pragma unroll
        for (int w = 1; w < 8; ++w) m = fmaxf(m, r1[w]);
        float scale = fmaxf(m, 1e-6f) / 127.0f;
        #pragma unroll
        for (int i = 0; i < 8; ++i) {
            float q = rintf(vals[i] / scale);
            q = fminf(fmaxf(q, -127.0f), 127.0f);
            wdq[t * 8 + i] = q * scale;
        }
    } else {
        // ---- init out[2b+1] = halt bias
        int b = (id - 769) * 512 + t;
        out[b * 2 + 1] = hb[0];
    }
}

// ============ K2: identical to passing R21 — 1024 blocks x 512 threads, select-free gather
__global__ __launch_bounds__(512) void k_back(const unsigned char* __restrict__ bits_b,
                                              const int* __restrict__ conn,
                                              const signed char* __restrict__ tq8,
                                              const float* __restrict__ tsc,
                                              const float* __restrict__ wdq,
                                              const unsigned short* __restrict__ hpart,
                                              const float* __restrict__ b1,
                                              const float* __restrict__ w2,
                                              const float* __restrict__ b2,
                                              float* __restrict__ out) {
    extern __shared__ char sm[];
    unsigned char* lbits = (unsigned char*)sm;         // [512 g][64 b]  32 KB
    signed char*   ltab  = (signed char*)(sm + 32768); // [128 m][256]   32 KB
    float*         red2  = (float*)(sm + 65536);       // [8][64]         2 KB

    int id = blockIdx.x;
    int t = threadIdx.x;                 // 0..511
    int lane = t & 63, wid = t >> 6;     // wid 0..7

    int swz = (id & 7) * 128 + (id >> 3);
    int bx = swz & 31, my = swz >> 5;
    int b0 = bx * 64, m0 = my * 128;

    for (int i = t; i < 2048; i += 512) {
        int g = i >> 2, q = i & 3;
        ((uint4*)lbits)[i] = *(const uint4*)(bits_b + (size_t)g * BB + b0 + q * 16);
    }
    for (int i = t; i < 2048; i += 512) {
        ((uint4*)ltab)[i] = *(const uint4*)(tq8 + (size_t)m0 * 256 + i * 16);
    }
    __syncthreads();

    int grp = lane >> 4;
    int bq  = lane & 15;
    float acc0 = 0.f, acc1 = 0.f, acc2 = 0.f, acc3 = 0.f;

    #pragma unroll
    for (int qi = 0; qi < 4; ++qi) {
        int mloc = wid * 16 + qi * 4 + grp;
        int mg   = m0 + mloc;
        float vw = tsc[mg] * wdq[mg];
        int4 ca = *(const int4*)(conn + (size_t)mg * 8);
        int4 cb = *(const int4*)(conn + (size_t)mg * 8 + 4);

        unsigned int aq = 0;
        #define GB(cv, kk) { \
            unsigned int w32 = *(const unsigned int*)(lbits + ((cv) >> 3) * 64 + bq * 4); \
            aq |= (((w32) >> ((cv) & 7)) & 0x01010101u) << (kk); }
        GB(ca.x, 0) GB(ca.y, 1) GB(ca.z, 2) GB(ca.w, 3)
        GB(cb.x, 4) GB(cb.y, 5) GB(cb.z, 6) GB(cb.w, 7)
        #undef GB

        const signed char* rowp = ltab + mloc * 256;
        float q0 = (float)rowp[aq & 255];
        float q1 = (float)rowp[(aq >> 8) & 255];
        float q2 = (float)rowp[(aq >> 16) & 255];
        float q3 = (float)rowp[aq >> 24];
        acc0 = fmaf(q0, vw, acc0); acc1 = fmaf(q1, vw, acc1);
        acc2 = fmaf(q2, vw, acc2); acc3 = fmaf(q3, vw, acc3);
    }

    acc0 += __shfl_xor(acc0, 16); acc1 += __shfl_xor(acc1, 16);
    acc2 += __shfl_xor(acc2, 16); acc3 += __shfl_xor(acc3, 16);
    acc0 += __shfl_xor(acc0, 32); acc1 += __shfl_xor(acc1, 32);
    acc2 += __shfl_xor(acc2, 32); acc3 += __shfl_xor(acc3, 32);
    if (lane < 16) {
        float4 o = make_float4(acc0, acc1, acc2, acc3);
        *(float4*)(red2 + wid * 64 + bq * 4) = o;
    }
    __syncthreads();
    if (t < 64) {
        float s = 0.f;
        #pragma unroll
        for (int w = 0; w < 8; ++w) s += red2[w * 64 + t];
        atomicAdd(&out[(size_t)(b0 + t) * 2 + 1], s);
    }

    if (wid < 2) {
        int b = id * 2 + wid;
        float s = 0.f;
        #pragma unroll
        for (int ks = 0; ks < KSPLIT; ++ks) s += bf2f(hpart[((size_t)ks * BB + b) * HH + lane]);
        s += b1[lane];
        s = fmaxf(s, 0.f);
        s *= w2[lane];
        #pragma unroll
        for (int off = 32; off; off >>= 1) s += __shfl_xor(s, off);
        if (lane == 0) out[b * 2] = s + b2[0];
    }
}

extern "C" void kernel_launch(void* const* d_in, const int* in_sizes, int n_in,
                              void* d_out, int out_size, void* d_ws, size_t ws_size,
                              hipStream_t stream) {
    const float* x    = (const float*)d_in[0];
    const float* tab  = (const float*)d_in[1];
    const float* w1   = (const float*)d_in[2];
    const float* b1   = (const float*)d_in[3];
    const float* w2   = (const float*)d_in[4];
    const float* b2   = (const float*)d_in[5];
    const float* hw   = (const float*)d_in[6];
    const float* hb   = (const float*)d_in[7];
    const int*   conn = (const int*)d_in[8];
    float* out = (float*)d_out;

    char* ws = (char*)d_ws;
    signed char*    tq8    = (signed char*)(ws);               //  1,048,576 B
    float*          tsc    = (float*)(ws + 1048576);           //     16,384 B
    float*          wdq    = (float*)(ws + 1064960);           //     16,384 B
    unsigned char*  bits_b = (unsigned char*)(ws + 1081344);   //  1,048,576 B
    unsigned short* hpart  = (unsigned short*)(ws + 2129920);  //  2,097,152 B (bf16, 8 splits)

    k_front<<<773, 512, 0, stream>>>(x, w1, tab, hw, hb, bits_b, tq8, tsc, wdq, hpart, out);
    k_back<<<1024, 512, 67584, stream>>>(bits_b, conn, tq8, tsc, wdq, hpart, b1, w2, b2, out);
}